// Round 1
// baseline (1263.301 us; speedup 1.0000x reference)
//
#include <hip/hip_runtime.h>

#define N_NODES 100000
#define N_EDGES 600000
#define D 128           // D_IN == D_OUT == 128
#define D4 32           // D / 4

// ---------------------------------------------------------------------------
// Kernel 1: edge scatter. One 32-lane group per edge; each lane gathers a
// float4 of features[src] and atomically adds it into agg[dst]. Lane 0 bumps
// the degree counter.
// ---------------------------------------------------------------------------
__global__ __launch_bounds__(256) void scatter_kernel(
    const float* __restrict__ feat,
    const int* __restrict__ src,
    const int* __restrict__ dst,
    float* __restrict__ agg,
    float* __restrict__ deg) {
    long long gid = (long long)blockIdx.x * blockDim.x + threadIdx.x;
    int e = (int)(gid >> 5);
    int q = (int)(gid & 31);
    if (e >= N_EDGES) return;
    int s = src[e];
    int d = dst[e];
    float4 v = reinterpret_cast<const float4*>(feat)[(size_t)s * D4 + q];
    float* outp = agg + (size_t)d * D + q * 4;
    atomicAdd(outp + 0, v.x);
    atomicAdd(outp + 1, v.y);
    atomicAdd(outp + 2, v.z);
    atomicAdd(outp + 3, v.w);
    if (q == 0) atomicAdd(deg + d, 1.0f);
}

// ---------------------------------------------------------------------------
// Kernel 2: fused norm + residual + GEMM (out = ((agg+feat)*norm) @ W^T + b).
// Block = 128 threads (2 waves). Thread j owns output column j and keeps the
// whole W row j in VGPRs (32 x float4). A tile of TN=8 node rows of
// h = (agg+feat)*norm is staged in LDS; the inner product reads hs with
// uniform-address (broadcast) ds_read_b128 -> no bank conflicts. 8
// independent accumulators give the FMA chain ILP.
// ---------------------------------------------------------------------------
#define TN 8  // nodes per tile

__global__ __launch_bounds__(128, 2) void gemm_kernel(
    const float* __restrict__ agg,
    const float* __restrict__ deg,
    const float* __restrict__ feat,
    const float* __restrict__ W,
    const float* __restrict__ b,
    float* __restrict__ out) {
    __shared__ float4 hs[TN][D4];

    const int j = threadIdx.x;  // output column, 0..127

    // Load W row j into registers (64KB total per block, L2-hot after warmup).
    float4 w[D4];
#pragma unroll
    for (int m = 0; m < D4; ++m) {
        w[m] = reinterpret_cast<const float4*>(W)[(size_t)j * D4 + m];
    }
    const float bj = b[j];

    const int ntiles = N_NODES / TN;  // 12500, exact
    for (int t = blockIdx.x; t < ntiles; t += gridDim.x) {
        const int n0 = t * TN;

        __syncthreads();  // protect hs against previous iteration's readers
        {
            // Stage h tile: thread (i = tid>>4, m16 = tid&15) loads 2 float4s
            // for node n0+i.
            const int i = threadIdx.x >> 4;   // 0..7
            const int m16 = threadIdx.x & 15; // 0..15
            const int n = n0 + i;
            const float dg = deg[n];
            const float nrm = rsqrtf(fmaxf(dg, 1.0f));
#pragma unroll
            for (int r = 0; r < 2; ++r) {
                const int c = m16 + r * 16;  // float4 index 0..31
                float4 a = reinterpret_cast<const float4*>(agg)[(size_t)n * D4 + c];
                float4 f = reinterpret_cast<const float4*>(feat)[(size_t)n * D4 + c];
                float4 h;
                h.x = (a.x + f.x) * nrm;
                h.y = (a.y + f.y) * nrm;
                h.z = (a.z + f.z) * nrm;
                h.w = (a.w + f.w) * nrm;
                hs[i][c] = h;
            }
        }
        __syncthreads();

        float acc[TN];
#pragma unroll
        for (int i = 0; i < TN; ++i) acc[i] = 0.0f;

#pragma unroll
        for (int m = 0; m < D4; ++m) {
            const float4 wm = w[m];
#pragma unroll
            for (int i = 0; i < TN; ++i) {
                const float4 h = hs[i][m];
                acc[i] = fmaf(h.x, wm.x,
                         fmaf(h.y, wm.y,
                         fmaf(h.z, wm.z,
                         fmaf(h.w, wm.w, acc[i]))));
            }
        }

#pragma unroll
        for (int i = 0; i < TN; ++i) {
            out[(size_t)(n0 + i) * D + j] = acc[i] + bj;
        }
    }
}

// ---------------------------------------------------------------------------
// Launch
// ---------------------------------------------------------------------------
extern "C" void kernel_launch(void* const* d_in, const int* in_sizes, int n_in,
                              void* d_out, int out_size, void* d_ws, size_t ws_size,
                              hipStream_t stream) {
    const float* feat = (const float*)d_in[0];
    const int*   src  = (const int*)d_in[1];
    const int*   dst  = (const int*)d_in[2];
    const float* W    = (const float*)d_in[3];
    const float* b    = (const float*)d_in[4];
    float* out = (float*)d_out;

    // Workspace layout: agg [N_NODES*D] f32, deg [N_NODES] f32.
    float* agg = (float*)d_ws;
    float* deg = agg + (size_t)N_NODES * D;

    // Zero agg + deg (harness poisons ws with 0xAA before every call).
    hipMemsetAsync(d_ws, 0, ((size_t)N_NODES * D + N_NODES) * sizeof(float),
                   stream);

    // Scatter: one 32-lane group per edge.
    {
        long long total = (long long)N_EDGES * 32;
        int block = 256;
        int grid = (int)((total + block - 1) / block);  // 75000
        scatter_kernel<<<grid, block, 0, stream>>>(feat, src, dst, agg, deg);
    }

    // Fused norm + GEMM.
    {
        int block = 128;
        int grid = 2048;  // grid-stride over 12500 tiles
        gemm_kernel<<<grid, block, 0, stream>>>(agg, deg, feat, W, b, out);
    }
}

// Round 2
// 291.980 us; speedup vs baseline: 4.3267x; 4.3267x over previous
//
#include <hip/hip_runtime.h>

#define N_NODES 100000
#define N_EDGES 600000
#define D 128
#define D4 32

#define SCAN_BLK 1024
#define NB ((N_NODES + SCAN_BLK - 1) / SCAN_BLK)  // 98

// ---------------------------------------------------------------------------
// CSR build: counts -> exclusive scan -> fill. Only int atomics (600K + 600K),
// no float atomics anywhere.
// ---------------------------------------------------------------------------
__global__ __launch_bounds__(256) void hist_kernel(
    const int* __restrict__ dst, int* __restrict__ counts) {
    int e = blockIdx.x * blockDim.x + threadIdx.x;
    if (e < N_EDGES) atomicAdd(&counts[dst[e]], 1);
}

// Per-block reduction of counts -> bsum[block]
__global__ __launch_bounds__(SCAN_BLK) void scanA_kernel(
    const int* __restrict__ counts, int* __restrict__ bsum) {
    __shared__ int sm[SCAN_BLK];
    int t = threadIdx.x;
    int i = blockIdx.x * SCAN_BLK + t;
    sm[t] = (i < N_NODES) ? counts[i] : 0;
    __syncthreads();
    for (int off = SCAN_BLK / 2; off > 0; off >>= 1) {
        if (t < off) sm[t] += sm[t + off];
        __syncthreads();
    }
    if (t == 0) bsum[blockIdx.x] = sm[0];
}

// Serial exclusive scan of the 98 block sums (trivial work).
__global__ __launch_bounds__(64) void scanB_kernel(int* __restrict__ bsum) {
    if (threadIdx.x == 0 && blockIdx.x == 0) {
        int run = 0;
        for (int i = 0; i < NB; ++i) {
            int v = bsum[i];
            bsum[i] = run;
            run += v;
        }
    }
}

// Per-block exclusive scan (Hillis-Steele) + block prefix -> offsets
__global__ __launch_bounds__(SCAN_BLK) void scanC_kernel(
    const int* __restrict__ counts, const int* __restrict__ bsum,
    int* __restrict__ offsets) {
    __shared__ int sm[SCAN_BLK];
    int t = threadIdx.x;
    int i = blockIdx.x * SCAN_BLK + t;
    int c = (i < N_NODES) ? counts[i] : 0;
    sm[t] = c;
    __syncthreads();
    for (int off = 1; off < SCAN_BLK; off <<= 1) {
        int v = (t >= off) ? sm[t - off] : 0;
        __syncthreads();
        sm[t] += v;
        __syncthreads();
    }
    if (i < N_NODES) offsets[i] = bsum[blockIdx.x] + sm[t] - c;  // exclusive
}

__global__ __launch_bounds__(256) void fill_kernel(
    const int* __restrict__ src, const int* __restrict__ dst,
    const int* __restrict__ offsets, int* __restrict__ cursor,
    int* __restrict__ csr) {
    int e = blockIdx.x * blockDim.x + threadIdx.x;
    if (e >= N_EDGES) return;
    int d = dst[e];
    int p = atomicAdd(&cursor[d], 1);
    csr[offsets[d] + p] = src[e];
}

// ---------------------------------------------------------------------------
// Fused gather + residual + degree-norm + GEMM.
// Block = 256 threads, TN = 16 nodes/tile, grid = 6250 (exact).
// Phase 1: 8 groups of 32 lanes; each group gathers 2 nodes. Lane q owns the
//   q-th float4 slice of the 512B feature row -> every row read is a fully
//   coalesced 512B burst. Accumulate in registers (init = residual feat[n]),
//   scale by rsqrt(max(deg,1)), stage into LDS.
// Phase 2: thread (j = tid&127, half = tid>>7) holds W row j in 32 float4
//   VGPRs, computes 8 node outputs from LDS broadcasts (conflict-free).
// ---------------------------------------------------------------------------
#define TN 16

__global__ __launch_bounds__(256, 2) void fused_kernel(
    const float* __restrict__ feat,
    const int* __restrict__ csr,
    const int* __restrict__ offsets,
    const int* __restrict__ counts,
    const float* __restrict__ W,
    const float* __restrict__ b,
    float* __restrict__ out) {
    __shared__ float4 hs[TN][D4];
    const float4* F4 = reinterpret_cast<const float4*>(feat);

    const int n0 = blockIdx.x * TN;

    // ---- Phase 1: gather ----
    {
        const int g = threadIdx.x >> 5;   // group 0..7
        const int q = threadIdx.x & 31;   // float4 slice 0..31
#pragma unroll
        for (int ii = 0; ii < TN / 8; ++ii) {
            const int ni = g + ii * 8;
            const int n = n0 + ni;
            const int row = offsets[n];
            const int degn = counts[n];
            float4 acc = F4[(size_t)n * D4 + q];  // residual
            int k = 0;
            const int kend4 = degn & ~3;
            for (; k < kend4; k += 4) {
                int s0 = csr[row + k + 0];
                int s1 = csr[row + k + 1];
                int s2 = csr[row + k + 2];
                int s3 = csr[row + k + 3];
                float4 v0 = F4[(size_t)s0 * D4 + q];
                float4 v1 = F4[(size_t)s1 * D4 + q];
                float4 v2 = F4[(size_t)s2 * D4 + q];
                float4 v3 = F4[(size_t)s3 * D4 + q];
                acc.x += (v0.x + v1.x) + (v2.x + v3.x);
                acc.y += (v0.y + v1.y) + (v2.y + v3.y);
                acc.z += (v0.z + v1.z) + (v2.z + v3.z);
                acc.w += (v0.w + v1.w) + (v2.w + v3.w);
            }
            for (; k < degn; ++k) {
                int s = csr[row + k];
                float4 v = F4[(size_t)s * D4 + q];
                acc.x += v.x; acc.y += v.y; acc.z += v.z; acc.w += v.w;
            }
            const float nrm = rsqrtf((float)(degn > 1 ? degn : 1));
            hs[ni][q] = make_float4(acc.x * nrm, acc.y * nrm,
                                    acc.z * nrm, acc.w * nrm);
        }
    }
    __syncthreads();

    // ---- Phase 2: GEMM ----
    const int j = threadIdx.x & 127;   // output column
    const int half = threadIdx.x >> 7; // node half (0: nodes 0..7, 1: 8..15)

    float4 w[D4];
#pragma unroll
    for (int m = 0; m < D4; ++m) {
        w[m] = reinterpret_cast<const float4*>(W)[(size_t)j * D4 + m];
    }
    const float bj = b[j];

    float acc[8];
#pragma unroll
    for (int i = 0; i < 8; ++i) acc[i] = 0.0f;

#pragma unroll
    for (int m = 0; m < D4; ++m) {
        const float4 wm = w[m];
#pragma unroll
        for (int i = 0; i < 8; ++i) {
            const float4 h = hs[half * 8 + i][m];
            acc[i] = fmaf(h.x, wm.x,
                     fmaf(h.y, wm.y,
                     fmaf(h.z, wm.z,
                     fmaf(h.w, wm.w, acc[i]))));
        }
    }

#pragma unroll
    for (int i = 0; i < 8; ++i) {
        out[(size_t)(n0 + half * 8 + i) * D + j] = acc[i] + bj;
    }
}

// ---------------------------------------------------------------------------
// Launch
// ---------------------------------------------------------------------------
extern "C" void kernel_launch(void* const* d_in, const int* in_sizes, int n_in,
                              void* d_out, int out_size, void* d_ws, size_t ws_size,
                              hipStream_t stream) {
    const float* feat = (const float*)d_in[0];
    const int*   src  = (const int*)d_in[1];
    const int*   dst  = (const int*)d_in[2];
    const float* W    = (const float*)d_in[3];
    const float* b    = (const float*)d_in[4];
    float* out = (float*)d_out;

    // Workspace layout (ints): counts | cursor | offsets | bsum(128) | csr
    int* counts  = (int*)d_ws;
    int* cursor  = counts + N_NODES;
    int* offsets = cursor + N_NODES;
    int* bsum    = offsets + N_NODES;
    int* csr     = bsum + 128;
    // total: 3*N_NODES + 128 + N_EDGES ints = ~3.6 MB (ws-safe)

    // Zero counts + cursor (contiguous).
    hipMemsetAsync(counts, 0, 2 * (size_t)N_NODES * sizeof(int), stream);

    const int eblocks = (N_EDGES + 255) / 256;  // 2344

    hist_kernel<<<eblocks, 256, 0, stream>>>(dst, counts);
    scanA_kernel<<<NB, SCAN_BLK, 0, stream>>>(counts, bsum);
    scanB_kernel<<<1, 64, 0, stream>>>(bsum);
    scanC_kernel<<<NB, SCAN_BLK, 0, stream>>>(counts, bsum, offsets);
    fill_kernel<<<eblocks, 256, 0, stream>>>(src, dst, offsets, cursor, csr);

    fused_kernel<<<N_NODES / TN, 256, 0, stream>>>(
        feat, csr, offsets, counts, W, b, out);
}